// Round 26
// baseline (40.100 us; speedup 1.0000x reference)
//
#include <hip/hip_runtime.h>

#define N_NODES 40000
#define N_EDGES 160000
#define N_FEATS 74
#define DD 1024
#define HD 3072
#define N_GRAPHS 800

#define NVB 192               // v-blocks: 16 g's per block (64 per head)
#define NTB 57                // task blocks: 222 L/R dots + c0
#define NCH 64                // scatter chunks
#define ECH (N_EDGES / NCH)   // 2500 edges per chunk
#define CAP 96                // slots per (range,chunk) cell (mean ~12.5)
#define SNR 200               // dst ranges (blocks in kMega)
#define SRNG 200              // dsts per range (= 4 graphs)

__device__ __forceinline__ float waveReduceSum(float v) {
    #pragma unroll
    for (int off = 32; off > 0; off >>= 1)
        v += __shfl_down(v, off, 64);
    return v;
}
__device__ __forceinline__ float lrelu02(float x) { return x > 0.f ? x : 0.2f * x; }

// ---- D1 kPre: weights (R22-proven) + private-cell scatter (R25-proven) ----
__global__ __launch_bounds__(256) void kPre(
    const float* __restrict__ W1, const float* __restrict__ W2,
    const float* __restrict__ b1, const float* __restrict__ b2,
    const float* __restrict__ W, const float* __restrict__ al,
    const float* __restrict__ ar, const float* __restrict__ bias,
    const int* __restrict__ dst,
    float* __restrict__ c0, float* __restrict__ bgvpar,
    float* __restrict__ wvpar, float* __restrict__ lw6,
    int* __restrict__ cnt, int* __restrict__ ebuf) {
    int wave = threadIdx.x >> 6, lane = threadIdx.x & 63;
    int tid = threadIdx.x;
    if (blockIdx.x < NVB) {
        __shared__ float vs[16];
        int b = blockIdx.x;
        int g0 = b * 16;
        int h = b >> 6;
        const float4* w2v = (const float4*)W2;
        #pragma unroll
        for (int q = 0; q < 4; ++q) {
            int g = g0 + wave * 4 + q;
            const float4* row = (const float4*)(W1 + (size_t)g * DD);
            float acc = 0.f;
            #pragma unroll
            for (int k = 0; k < 4; ++k) {
                float4 a = row[lane + 64 * k];
                float4 bb = w2v[lane + 64 * k];
                acc += a.x * bb.x + a.y * bb.y + a.z * bb.z + a.w * bb.w;
            }
            acc = waveReduceSum(acc);
            if (!lane) vs[wave * 4 + q] = acc;
        }
        __syncthreads();
        if (tid < N_FEATS) {
            const float4* wr = (const float4*)(W + (size_t)tid * HD + g0);
            const float4* vv = (const float4*)vs;
            float s = 0.f;
            #pragma unroll
            for (int k = 0; k < 4; ++k) {
                float4 a = wr[k];
                float4 bb = vv[k];
                s += a.x * bb.x + a.y * bb.y + a.z * bb.z + a.w * bb.w;
            }
            wvpar[((size_t)(h * N_FEATS + tid)) * 64 + (b & 63)] = s;  // transposed
        } else if (tid == N_FEATS) {
            float s = 0.f;
            #pragma unroll
            for (int j = 0; j < 16; ++j) s += vs[j] * bias[g0 + j];
            bgvpar[b] = s;
        }
    } else if (blockIdx.x < NVB + NTB) {
        int t = (blockIdx.x - NVB) * 4 + wave;
        if (t < N_FEATS * 3) {
            int f = t / 3, h = t - f * 3;
            const float4* rw = (const float4*)(W + (size_t)f * HD + h * DD);
            const float4* pl = (const float4*)(al + h * DD);
            const float4* pr = (const float4*)(ar + h * DD);
            float aL = 0.f, aR = 0.f;
            #pragma unroll
            for (int k = 0; k < 4; ++k) {
                float4 x = rw[lane + 64 * k];
                float4 l4 = pl[lane + 64 * k];
                float4 r4 = pr[lane + 64 * k];
                aL += x.x * l4.x + x.y * l4.y + x.z * l4.z + x.w * l4.w;
                aR += x.x * r4.x + x.y * r4.y + x.z * r4.z + x.w * r4.w;
            }
            aL = waveReduceSum(aL); aR = waveReduceSum(aR);
            if (!lane) { lw6[f * 6 + h] = aL; lw6[f * 6 + 3 + h] = aR; }
        } else if (t == N_FEATS * 3) {
            const float4* pb1 = (const float4*)b1;
            const float4* w2v = (const float4*)W2;
            float acc = 0.f;
            #pragma unroll
            for (int k = 0; k < 4; ++k) {
                float4 a = pb1[lane + 64 * k];
                float4 bb = w2v[lane + 64 * k];
                acc += a.x * bb.x + a.y * bb.y + a.z * bb.z + a.w * bb.w;
            }
            acc = waveReduceSum(acc);
            if (!lane) c0[0] = acc + b2[0];
        }
    } else {
        // scatter block: chunk c places edges into its private (r,c) cells
        __shared__ int cur[SNR];
        int c = blockIdx.x - (NVB + NTB);
        for (int i = tid; i < SNR; i += 256) cur[i] = 0;
        __syncthreads();
        const int eb = c * ECH;
        for (int i = tid; i < ECH; i += 256) {
            int e = eb + i;
            int d = dst[e];
            int r = d / SRNG;
            int rr = d - r * SRNG;
            int slot = atomicAdd(&cur[r], 1);
            ebuf[(r * NCH + c) * CAP + slot] = (e << 8) | rr;
        }
        __syncthreads();
        for (int i = tid; i < SNR; i += 256) cnt[c * SNR + i] = cur[i];
    }
}

// ---- D2 kMega: lw build + own-er + dense 8-lane on-demand processing + pool ----
__global__ __launch_bounds__(1024) void kMega(const float* __restrict__ feats,
        const int* __restrict__ src, const int* __restrict__ ebuf,
        const int* __restrict__ cnt,
        const float* __restrict__ lw6, const float* __restrict__ wvpar,
        const float* __restrict__ bgvpar, const float* __restrict__ c0,
        float* __restrict__ y) {
    __shared__ float lw[N_FEATS * 9];   // 2.7 KB
    __shared__ float erL[SRNG * 4];     // 3.2 KB
    __shared__ float acc[SRNG * 6];     // 4.8 KB
    __shared__ int cnts[NCH];
    __shared__ int pref[NCH + 1];
    int tid = threadIdx.x, wave = tid >> 6, lane = tid & 63;
    const int r = blockIdx.x;
    // phase 1: zero acc; V-table (4-lane coalesced); L/R direct; cnts
    for (int i = tid; i < SRNG * 6; i += 1024) acc[i] = 0.f;
    if (tid < 222 * 4) {
        int g4 = tid >> 2, sl = tid & 3;     // g4 = h*74+f
        int h = g4 / N_FEATS, f = g4 - h * N_FEATS;
        const float* p = wvpar + (size_t)g4 * 64 + sl * 16;
        float s = 0.f;
        #pragma unroll
        for (int k = 0; k < 16; ++k) s += p[k];
        s += __shfl_xor(s, 1, 64);
        s += __shfl_xor(s, 2, 64);
        if (!sl) lw[f * 9 + 6 + h] = s;
    }
    if (tid < N_FEATS * 6)
        lw[(tid / 6) * 9 + (tid % 6)] = lw6[tid];
    if (tid < NCH) cnts[tid] = cnt[tid * SNR + r];
    __syncthreads();
    if (tid == 0) {
        int b = 0;
        #pragma unroll
        for (int c = 0; c < NCH; ++c) { pref[c] = b; b += cnts[c]; }
        pref[NCH] = b;
    }
    // phase 2: er for own 200 dsts (8-lane groups, R22-proven)
    for (int base = 0; base < SRNG * 3; base += 128) {
        int task = base + (tid >> 3);
        int sl = tid & 7;
        if (task < SRNG * 3) {
            int nloc = task / 3, h = task - nloc * 3;
            const float2* fr2 = (const float2*)(feats + (size_t)(r * SRNG + nloc) * N_FEATS);
            float s = 0.f;
            #pragma unroll
            for (int k = 0; k < 5; ++k) {
                int j = sl + 8 * k;
                if (j < 37) {
                    float2 x2 = fr2[j];
                    s += x2.x * lw[(2 * j) * 9 + 3 + h] + x2.y * lw[(2 * j + 1) * 9 + 3 + h];
                }
            }
            #pragma unroll
            for (int m = 1; m < 8; m <<= 1) s += __shfl_xor(s, m, 64);
            if (!sl) erL[nloc * 4 + h] = s;
        }
    }
    __syncthreads();
    // phase 3: dense processing, 8 lanes per edge, on-demand src projection
    int T = pref[NCH];
    int sl = tid & 7;
    for (int i = tid >> 3; i < T; i += 128) {
        int lo = 0, hi = NCH;
        while (hi - lo > 1) {
            int mid = (lo + hi) >> 1;
            if (pref[mid] <= i) lo = mid; else hi = mid;
        }
        int j = i - pref[lo];
        int pk = ebuf[(r * NCH + lo) * CAP + j];
        int rr = pk & 255;
        int e  = ((unsigned)pk) >> 8;
        int s  = src[e];
        const float2* fr2 = (const float2*)(feats + (size_t)s * N_FEATS);
        float el0=0,el1=0,el2=0,hv0=0,hv1=0,hv2=0;
        #pragma unroll
        for (int k = 0; k < 5; ++k) {
            int jj = sl + 8 * k;
            if (jj < 37) {
                float2 x2 = fr2[jj];
                const float* wA = lw + (2 * jj) * 9;
                el0 += x2.x*wA[0]; el1 += x2.x*wA[1]; el2 += x2.x*wA[2];
                hv0 += x2.x*wA[6]; hv1 += x2.x*wA[7]; hv2 += x2.x*wA[8];
                const float* wB = wA + 9;
                el0 += x2.y*wB[0]; el1 += x2.y*wB[1]; el2 += x2.y*wB[2];
                hv0 += x2.y*wB[6]; hv1 += x2.y*wB[7]; hv2 += x2.y*wB[8];
            }
        }
        #pragma unroll
        for (int m = 1; m < 8; m <<= 1) {
            el0 += __shfl_xor(el0, m, 64); el1 += __shfl_xor(el1, m, 64);
            el2 += __shfl_xor(el2, m, 64);
            hv0 += __shfl_xor(hv0, m, 64); hv1 += __shfl_xor(hv1, m, 64);
            hv2 += __shfl_xor(hv2, m, 64);
        }
        if (sl == 0) {
            const float* er = erL + rr * 4;
            float e0 = expf(lrelu02(el0 + er[0]));
            float e1 = expf(lrelu02(el1 + er[1]));
            float e2 = expf(lrelu02(el2 + er[2]));
            float* p = acc + rr * 6;
            atomicAdd(p + 0, e0 * hv0);
            atomicAdd(p + 1, e1 * hv1);
            atomicAdd(p + 2, e2 * hv2);
            atomicAdd(p + 3, e0);
            atomicAdd(p + 4, e1);
            atomicAdd(p + 5, e2);
        }
    }
    __syncthreads();
    // phase 4: pooling, waves 0..3 -> graphs r*4 + wave
    if (wave < 4) {
        float b = 0.f;
        for (int i = lane; i < NVB; i += 64) b += bgvpar[i];
        b = waveReduceSum(b);
        float cacc = 0.f;
        if (lane < 50) {
            const float* p = acc + (wave * 50 + lane) * 6;
            if (p[3] > 0.f) cacc = p[0] / p[3] + p[1] / p[4] + p[2] / p[5];
        }
        cacc = waveReduceSum(cacc);
        if (!lane) y[r * 4 + wave] = cacc * (1.f / 50.f) + b + c0[0];
    }
}

extern "C" void kernel_launch(void* const* d_in, const int* in_sizes, int n_in,
                              void* d_out, int out_size, void* d_ws, size_t ws_size,
                              hipStream_t stream) {
    const float* feats = (const float*)d_in[0];
    const float* W     = (const float*)d_in[1];
    const float* al    = (const float*)d_in[2];
    const float* ar    = (const float*)d_in[3];
    const float* bias  = (const float*)d_in[4];
    const float* W1    = (const float*)d_in[5];
    const float* b1    = (const float*)d_in[6];
    const float* W2    = (const float*)d_in[7];
    const float* b2    = (const float*)d_in[8];
    const int*   src   = (const int*)d_in[9];
    const int*   dst   = (const int*)d_in[10];

    float* ws      = (float*)d_ws;
    float* lw6     = ws;                      // 444 (pad 448)
    float* c0      = ws + 448;                // 1
    float* bgvpar  = ws + 512;                // 192
    float* wvpar   = ws + 1024;               // 222*64 = 14208
    int*   cnt     = (int*)(ws + 16384);      // 64*200 = 12800
    int*   ebuf    = (int*)(ws + 32768);      // 200*64*96 = 1228800
    float* y       = (float*)d_out;

    hipLaunchKernelGGL(kPre, dim3(NVB + NTB + NCH), dim3(256), 0, stream,
                       W1, W2, b1, b2, W, al, ar, bias, dst,
                       c0, bgvpar, wvpar, lw6, cnt, ebuf);
    hipLaunchKernelGGL(kMega, dim3(SNR), dim3(1024), 0, stream,
                       feats, src, ebuf, cnt, lw6, wvpar, bgvpar, c0, y);
}

// Round 27
// 36.430 us; speedup vs baseline: 1.1008x; 1.1008x over previous
//
#include <hip/hip_runtime.h>

#define N_NODES 40000
#define N_EDGES 160000
#define N_FEATS 74
#define DD 1024
#define HD 3072
#define N_GRAPHS 800

#define NVB 192               // v-blocks: 16 g's per block (64 per head)
#define NTB 57                // task blocks: 222 L/R dots + c0
#define NCH 64                // scatter chunks
#define ECH (N_EDGES / NCH)   // 2500 edges per chunk
#define CAP 96                // slots per (range,chunk) cell (mean ~12.5)
#define SNR 200               // dst ranges (blocks in kProcess)
#define SRNG 200              // dsts per range (= 4 graphs)
#define NNB 313               // node blocks ((N_NODES+127)/128)

__device__ __forceinline__ float waveReduceSum(float v) {
    #pragma unroll
    for (int off = 32; off > 0; off >>= 1)
        v += __shfl_down(v, off, 64);
    return v;
}
__device__ __forceinline__ float lrelu02(float x) { return x > 0.f ? x : 0.2f * x; }

// ---- D1 kPre: weights (R22-proven) + src-packing cell scatter ----
__global__ __launch_bounds__(256) void kPre(
    const float* __restrict__ W1, const float* __restrict__ W2,
    const float* __restrict__ b1, const float* __restrict__ b2,
    const float* __restrict__ W, const float* __restrict__ al,
    const float* __restrict__ ar, const float* __restrict__ bias,
    const int* __restrict__ src, const int* __restrict__ dst,
    float* __restrict__ c0, float* __restrict__ bgvpar,
    float* __restrict__ wvpar, float* __restrict__ lw6,
    int* __restrict__ cnt, int* __restrict__ ebuf) {
    int wave = threadIdx.x >> 6, lane = threadIdx.x & 63;
    int tid = threadIdx.x;
    if (blockIdx.x < NVB) {
        __shared__ float vs[16];
        int b = blockIdx.x;
        int g0 = b * 16;
        int h = b >> 6;
        const float4* w2v = (const float4*)W2;
        #pragma unroll
        for (int q = 0; q < 4; ++q) {
            int g = g0 + wave * 4 + q;
            const float4* row = (const float4*)(W1 + (size_t)g * DD);
            float acc = 0.f;
            #pragma unroll
            for (int k = 0; k < 4; ++k) {
                float4 a = row[lane + 64 * k];
                float4 bb = w2v[lane + 64 * k];
                acc += a.x * bb.x + a.y * bb.y + a.z * bb.z + a.w * bb.w;
            }
            acc = waveReduceSum(acc);
            if (!lane) vs[wave * 4 + q] = acc;
        }
        __syncthreads();
        if (tid < N_FEATS) {
            const float4* wr = (const float4*)(W + (size_t)tid * HD + g0);
            const float4* vv = (const float4*)vs;
            float s = 0.f;
            #pragma unroll
            for (int k = 0; k < 4; ++k) {
                float4 a = wr[k];
                float4 bb = vv[k];
                s += a.x * bb.x + a.y * bb.y + a.z * bb.z + a.w * bb.w;
            }
            wvpar[((size_t)(h * N_FEATS + tid)) * 64 + (b & 63)] = s;  // transposed
        } else if (tid == N_FEATS) {
            float s = 0.f;
            #pragma unroll
            for (int j = 0; j < 16; ++j) s += vs[j] * bias[g0 + j];
            bgvpar[b] = s;
        }
    } else if (blockIdx.x < NVB + NTB) {
        int t = (blockIdx.x - NVB) * 4 + wave;
        if (t < N_FEATS * 3) {
            int f = t / 3, h = t - f * 3;
            const float4* rw = (const float4*)(W + (size_t)f * HD + h * DD);
            const float4* pl = (const float4*)(al + h * DD);
            const float4* pr = (const float4*)(ar + h * DD);
            float aL = 0.f, aR = 0.f;
            #pragma unroll
            for (int k = 0; k < 4; ++k) {
                float4 x = rw[lane + 64 * k];
                float4 l4 = pl[lane + 64 * k];
                float4 r4 = pr[lane + 64 * k];
                aL += x.x * l4.x + x.y * l4.y + x.z * l4.z + x.w * l4.w;
                aR += x.x * r4.x + x.y * r4.y + x.z * r4.z + x.w * r4.w;
            }
            aL = waveReduceSum(aL); aR = waveReduceSum(aR);
            if (!lane) { lw6[f * 6 + h] = aL; lw6[f * 6 + 3 + h] = aR; }
        } else if (t == N_FEATS * 3) {
            const float4* pb1 = (const float4*)b1;
            const float4* w2v = (const float4*)W2;
            float acc = 0.f;
            #pragma unroll
            for (int k = 0; k < 4; ++k) {
                float4 a = pb1[lane + 64 * k];
                float4 bb = w2v[lane + 64 * k];
                acc += a.x * bb.x + a.y * bb.y + a.z * bb.z + a.w * bb.w;
            }
            acc = waveReduceSum(acc);
            if (!lane) c0[0] = acc + b2[0];
        }
    } else {
        // scatter block: chunk c -> private (r,c) cells; entry packs (src<<8)|rr
        __shared__ int cur[SNR];
        int c = blockIdx.x - (NVB + NTB);
        for (int i = tid; i < SNR; i += 256) cur[i] = 0;
        __syncthreads();
        const int eb = c * ECH;
        for (int i = tid; i < ECH; i += 256) {
            int e = eb + i;
            int d = dst[e];
            int r = d / SRNG;
            int rr = d - r * SRNG;
            int slot = atomicAdd(&cur[r], 1);
            ebuf[(r * NCH + c) * CAP + slot] = (src[e] << 8) | rr;
        }
        __syncthreads();
        for (int i = tid; i < SNR; i += 256) cnt[c * SNR + i] = cur[i];
    }
}

// ---- D2 kNode: pure node projections (R18/R22-proven body) ----
__global__ __launch_bounds__(256) void kNode(const float* __restrict__ feats,
        const float* __restrict__ lw6, const float* __restrict__ wvpar,
        float4* __restrict__ sn4, float4* __restrict__ er4) {
    __shared__ float lw[N_FEATS * 9];
    int tid = threadIdx.x;
    for (int j = tid; j < 222 * 4; j += 256) {
        int g4 = j >> 2, sl = j & 3;     // g4 = h*74+f
        int h = g4 / N_FEATS, f = g4 - h * N_FEATS;
        const float* p = wvpar + (size_t)g4 * 64 + sl * 16;
        float s = 0.f;
        #pragma unroll
        for (int k = 0; k < 16; ++k) s += p[k];
        s += __shfl_xor(s, 1, 64);
        s += __shfl_xor(s, 2, 64);
        if (!sl) lw[f * 9 + 6 + h] = s;
    }
    for (int i = tid; i < N_FEATS * 6; i += 256)
        lw[(i / 6) * 9 + (i % 6)] = lw6[i];
    __syncthreads();
    int node = blockIdx.x * 128 + (tid >> 1);
    if (node >= N_NODES) return;
    int half = tid & 1;
    const float* row = feats + (size_t)node * N_FEATS;
    float a0=0,a1=0,a2=0,a3=0,a4=0,a5=0,a6=0,a7=0,a8=0;
    if (half == 0) {
        #pragma unroll
        for (int k = 0; k < 18; ++k) {
            float2 x2 = *(const float2*)(row + k * 2);
            const float* w0 = lw + (k * 2) * 9;
            a0 += x2.x*w0[0]; a1 += x2.x*w0[1]; a2 += x2.x*w0[2];
            a3 += x2.x*w0[3]; a4 += x2.x*w0[4]; a5 += x2.x*w0[5];
            a6 += x2.x*w0[6]; a7 += x2.x*w0[7]; a8 += x2.x*w0[8];
            const float* w1 = w0 + 9;
            a0 += x2.y*w1[0]; a1 += x2.y*w1[1]; a2 += x2.y*w1[2];
            a3 += x2.y*w1[3]; a4 += x2.y*w1[4]; a5 += x2.y*w1[5];
            a6 += x2.y*w1[6]; a7 += x2.y*w1[7]; a8 += x2.y*w1[8];
        }
        float x = row[36];
        const float* wp = lw + 36 * 9;
        a0 += x*wp[0]; a1 += x*wp[1]; a2 += x*wp[2];
        a3 += x*wp[3]; a4 += x*wp[4]; a5 += x*wp[5];
        a6 += x*wp[6]; a7 += x*wp[7]; a8 += x*wp[8];
    } else {
        float x = row[37];
        const float* wp = lw + 37 * 9;
        a0 += x*wp[0]; a1 += x*wp[1]; a2 += x*wp[2];
        a3 += x*wp[3]; a4 += x*wp[4]; a5 += x*wp[5];
        a6 += x*wp[6]; a7 += x*wp[7]; a8 += x*wp[8];
        #pragma unroll
        for (int k = 0; k < 18; ++k) {
            float2 x2 = *(const float2*)(row + 38 + k * 2);
            const float* w0 = lw + (38 + k * 2) * 9;
            a0 += x2.x*w0[0]; a1 += x2.x*w0[1]; a2 += x2.x*w0[2];
            a3 += x2.x*w0[3]; a4 += x2.x*w0[4]; a5 += x2.x*w0[5];
            a6 += x2.x*w0[6]; a7 += x2.x*w0[7]; a8 += x2.x*w0[8];
            const float* w1 = w0 + 9;
            a0 += x2.y*w1[0]; a1 += x2.y*w1[1]; a2 += x2.y*w1[2];
            a3 += x2.y*w1[3]; a4 += x2.y*w1[4]; a5 += x2.y*w1[5];
            a6 += x2.y*w1[6]; a7 += x2.y*w1[7]; a8 += x2.y*w1[8];
        }
    }
    a0 += __shfl_xor(a0, 1, 64); a1 += __shfl_xor(a1, 1, 64);
    a2 += __shfl_xor(a2, 1, 64); a3 += __shfl_xor(a3, 1, 64);
    a4 += __shfl_xor(a4, 1, 64); a5 += __shfl_xor(a5, 1, 64);
    a6 += __shfl_xor(a6, 1, 64); a7 += __shfl_xor(a7, 1, 64);
    a8 += __shfl_xor(a8, 1, 64);
    if (!half) {
        sn4[node * 2]     = make_float4(a0, a1, a2, 0.f);  // el
        sn4[node * 2 + 1] = make_float4(a6, a7, a8, 0.f);  // hv
        er4[node]         = make_float4(a3, a4, a5, 0.f);
    }
}

// ---- D3 kProcess: cell-walk dense processing + fused pooling ----
__global__ __launch_bounds__(1024) void kProcess(
        const int* __restrict__ ebuf, const int* __restrict__ cnt,
        const float4* __restrict__ sn4, const float4* __restrict__ er4,
        const float* __restrict__ bgvpar, const float* __restrict__ c0,
        float* __restrict__ y) {
    __shared__ float erL[SRNG * 4];   // 3.2 KB
    __shared__ float acc[SRNG * 6];   // 4.8 KB
    __shared__ int pref[NCH + 1];
    __shared__ int cnts[NCH];
    int tid = threadIdx.x, wave = tid >> 6, lane = tid & 63;
    const int r = blockIdx.x;
    if (tid < NCH) cnts[tid] = cnt[tid * SNR + r];
    for (int i = tid; i < SRNG * 6; i += 1024) acc[i] = 0.f;
    if (tid < SRNG) ((float4*)erL)[tid] = er4[(size_t)r * SRNG + tid];
    __syncthreads();
    if (tid == 0) {
        int b = 0;
        #pragma unroll
        for (int c = 0; c < NCH; ++c) { pref[c] = b; b += cnts[c]; }
        pref[NCH] = b;
    }
    __syncthreads();
    int T = pref[NCH];
    for (int i = tid; i < T; i += 1024) {
        int lo = 0, hi = NCH;
        while (hi - lo > 1) {
            int mid = (lo + hi) >> 1;
            if (pref[mid] <= i) lo = mid; else hi = mid;
        }
        int j = i - pref[lo];
        int pk = ebuf[(r * NCH + lo) * CAP + j];
        int rr = pk & 255;
        int s  = ((unsigned)pk) >> 8;         // src packed at scatter time
        float4 L = sn4[s * 2];
        float4 V = sn4[s * 2 + 1];
        const float* R = erL + rr * 4;
        float e0 = expf(lrelu02(L.x + R[0]));
        float e1 = expf(lrelu02(L.y + R[1]));
        float e2 = expf(lrelu02(L.z + R[2]));
        float* p = acc + rr * 6;
        atomicAdd(p + 0, e0 * V.x);
        atomicAdd(p + 1, e1 * V.y);
        atomicAdd(p + 2, e2 * V.z);
        atomicAdd(p + 3, e0);
        atomicAdd(p + 4, e1);
        atomicAdd(p + 5, e2);
    }
    __syncthreads();
    if (wave < 4) {
        float b = 0.f;
        for (int i = lane; i < NVB; i += 64) b += bgvpar[i];
        b = waveReduceSum(b);
        float cacc = 0.f;
        if (lane < 50) {
            const float* p = acc + (wave * 50 + lane) * 6;
            if (p[3] > 0.f) cacc = p[0] / p[3] + p[1] / p[4] + p[2] / p[5];
        }
        cacc = waveReduceSum(cacc);
        if (!lane) y[r * 4 + wave] = cacc * (1.f / 50.f) + b + c0[0];
    }
}

extern "C" void kernel_launch(void* const* d_in, const int* in_sizes, int n_in,
                              void* d_out, int out_size, void* d_ws, size_t ws_size,
                              hipStream_t stream) {
    const float* feats = (const float*)d_in[0];
    const float* W     = (const float*)d_in[1];
    const float* al    = (const float*)d_in[2];
    const float* ar    = (const float*)d_in[3];
    const float* bias  = (const float*)d_in[4];
    const float* W1    = (const float*)d_in[5];
    const float* b1    = (const float*)d_in[6];
    const float* W2    = (const float*)d_in[7];
    const float* b2    = (const float*)d_in[8];
    const int*   src   = (const int*)d_in[9];
    const int*   dst   = (const int*)d_in[10];

    float* ws      = (float*)d_ws;
    float* lw6     = ws;                      // 444 (pad 448)
    float* c0      = ws + 448;                // 1
    float* bgvpar  = ws + 512;                // 192
    float* wvpar   = ws + 1024;               // 222*64 = 14208
    int*   cnt     = (int*)(ws + 16384);      // 64*200 = 12800
    int*   ebuf    = (int*)(ws + 32768);      // 200*64*96 = 1228800
    float* sn      = ws + 1261568;            // N*8 (16B aligned)
    float* er      = sn + N_NODES * 8;        // N*4
    float* y       = (float*)d_out;

    hipLaunchKernelGGL(kPre, dim3(NVB + NTB + NCH), dim3(256), 0, stream,
                       W1, W2, b1, b2, W, al, ar, bias, src, dst,
                       c0, bgvpar, wvpar, lw6, cnt, ebuf);
    hipLaunchKernelGGL(kNode, dim3(NNB), dim3(256), 0, stream,
                       feats, lw6, wvpar, (float4*)sn, (float4*)er);
    hipLaunchKernelGGL(kProcess, dim3(SNR), dim3(1024), 0, stream,
                       ebuf, cnt, (const float4*)sn, (const float4*)er,
                       bgvpar, c0, y);
}

// Round 28
// 35.195 us; speedup vs baseline: 1.1394x; 1.0351x over previous
//
#include <hip/hip_runtime.h>

#define N_NODES 40000
#define N_EDGES 160000
#define N_FEATS 74
#define DD 1024
#define HD 3072
#define N_GRAPHS 800

#define NVB 192               // v-blocks: 16 g's per block (64 per head)
#define NTB 57                // task blocks: 222 L/R dots + c0
#define NCH 64                // scatter chunks
#define ECH (N_EDGES / NCH)   // 2500 edges per chunk
#define CAP 96                // slots per (range,chunk) cell (mean ~12.5)
#define SNR 200               // dst ranges (blocks in kProcess)
#define SRNG 200              // dsts per range (= 4 graphs)
#define NNB 313               // node blocks ((N_NODES+127)/128)

__device__ __forceinline__ float waveReduceSum(float v) {
    #pragma unroll
    for (int off = 32; off > 0; off >>= 1)
        v += __shfl_down(v, off, 64);
    return v;
}
__device__ __forceinline__ float lrelu02(float x) { return x > 0.f ? x : 0.2f * x; }

// ---- D1 kPre: weights (R22-proven) + direct cell-scatter blocks ----
__global__ __launch_bounds__(256) void kPre(
    const float* __restrict__ W1, const float* __restrict__ W2,
    const float* __restrict__ b1, const float* __restrict__ b2,
    const float* __restrict__ W, const float* __restrict__ al,
    const float* __restrict__ ar, const float* __restrict__ bias,
    const int* __restrict__ dst,
    float* __restrict__ c0, float* __restrict__ bgvpar,
    float* __restrict__ wvpar, float* __restrict__ lw6,
    int* __restrict__ cnt, int* __restrict__ ebuf) {
    int wave = threadIdx.x >> 6, lane = threadIdx.x & 63;
    int tid = threadIdx.x;
    if (blockIdx.x < NVB) {
        __shared__ float vs[16];
        int b = blockIdx.x;
        int g0 = b * 16;
        int h = b >> 6;
        const float4* w2v = (const float4*)W2;
        #pragma unroll
        for (int q = 0; q < 4; ++q) {
            int g = g0 + wave * 4 + q;
            const float4* row = (const float4*)(W1 + (size_t)g * DD);
            float acc = 0.f;
            #pragma unroll
            for (int k = 0; k < 4; ++k) {
                float4 a = row[lane + 64 * k];
                float4 bb = w2v[lane + 64 * k];
                acc += a.x * bb.x + a.y * bb.y + a.z * bb.z + a.w * bb.w;
            }
            acc = waveReduceSum(acc);
            if (!lane) vs[wave * 4 + q] = acc;
        }
        __syncthreads();
        if (tid < N_FEATS) {
            const float4* wr = (const float4*)(W + (size_t)tid * HD + g0);
            const float4* vv = (const float4*)vs;
            float s = 0.f;
            #pragma unroll
            for (int k = 0; k < 4; ++k) {
                float4 a = wr[k];
                float4 bb = vv[k];
                s += a.x * bb.x + a.y * bb.y + a.z * bb.z + a.w * bb.w;
            }
            wvpar[((size_t)(h * N_FEATS + tid)) * 64 + (b & 63)] = s;  // transposed
        } else if (tid == N_FEATS) {
            float s = 0.f;
            #pragma unroll
            for (int j = 0; j < 16; ++j) s += vs[j] * bias[g0 + j];
            bgvpar[b] = s;
        }
    } else if (blockIdx.x < NVB + NTB) {
        int t = (blockIdx.x - NVB) * 4 + wave;
        if (t < N_FEATS * 3) {
            int f = t / 3, h = t - f * 3;
            const float4* rw = (const float4*)(W + (size_t)f * HD + h * DD);
            const float4* pl = (const float4*)(al + h * DD);
            const float4* pr = (const float4*)(ar + h * DD);
            float aL = 0.f, aR = 0.f;
            #pragma unroll
            for (int k = 0; k < 4; ++k) {
                float4 x = rw[lane + 64 * k];
                float4 l4 = pl[lane + 64 * k];
                float4 r4 = pr[lane + 64 * k];
                aL += x.x * l4.x + x.y * l4.y + x.z * l4.z + x.w * l4.w;
                aR += x.x * r4.x + x.y * r4.y + x.z * r4.z + x.w * r4.w;
            }
            aL = waveReduceSum(aL); aR = waveReduceSum(aR);
            if (!lane) { lw6[f * 6 + h] = aL; lw6[f * 6 + 3 + h] = aR; }
        } else if (t == N_FEATS * 3) {
            const float4* pb1 = (const float4*)b1;
            const float4* w2v = (const float4*)W2;
            float acc = 0.f;
            #pragma unroll
            for (int k = 0; k < 4; ++k) {
                float4 a = pb1[lane + 64 * k];
                float4 bb = w2v[lane + 64 * k];
                acc += a.x * bb.x + a.y * bb.y + a.z * bb.z + a.w * bb.w;
            }
            acc = waveReduceSum(acc);
            if (!lane) c0[0] = acc + b2[0];
        }
    } else {
        // scatter block: chunk c places edges into its private (r,c) cells
        __shared__ int cur[SNR];
        int c = blockIdx.x - (NVB + NTB);
        for (int i = tid; i < SNR; i += 256) cur[i] = 0;
        __syncthreads();
        const int eb = c * ECH;
        for (int i = tid; i < ECH; i += 256) {
            int e = eb + i;
            int d = dst[e];
            int r = d / SRNG;
            int rr = d - r * SRNG;
            int slot = atomicAdd(&cur[r], 1);
            ebuf[(r * NCH + c) * CAP + slot] = (e << 8) | rr;
        }
        __syncthreads();
        for (int i = tid; i < SNR; i += 256) cnt[c * SNR + i] = cur[i];
    }
}

// ---- D2 kNode: pure node projections (R18/R22-proven body) ----
__global__ __launch_bounds__(256) void kNode(const float* __restrict__ feats,
        const float* __restrict__ lw6, const float* __restrict__ wvpar,
        float4* __restrict__ sn4, float4* __restrict__ er4) {
    __shared__ float lw[N_FEATS * 9];
    int tid = threadIdx.x;
    for (int j = tid; j < 222 * 4; j += 256) {
        int g4 = j >> 2, sl = j & 3;     // g4 = h*74+f
        int h = g4 / N_FEATS, f = g4 - h * N_FEATS;
        const float* p = wvpar + (size_t)g4 * 64 + sl * 16;
        float s = 0.f;
        #pragma unroll
        for (int k = 0; k < 16; ++k) s += p[k];
        s += __shfl_xor(s, 1, 64);
        s += __shfl_xor(s, 2, 64);
        if (!sl) lw[f * 9 + 6 + h] = s;
    }
    for (int i = tid; i < N_FEATS * 6; i += 256)
        lw[(i / 6) * 9 + (i % 6)] = lw6[i];
    __syncthreads();
    int node = blockIdx.x * 128 + (tid >> 1);
    if (node >= N_NODES) return;
    int half = tid & 1;
    const float* row = feats + (size_t)node * N_FEATS;
    float a0=0,a1=0,a2=0,a3=0,a4=0,a5=0,a6=0,a7=0,a8=0;
    if (half == 0) {
        #pragma unroll
        for (int k = 0; k < 18; ++k) {
            float2 x2 = *(const float2*)(row + k * 2);
            const float* w0 = lw + (k * 2) * 9;
            a0 += x2.x*w0[0]; a1 += x2.x*w0[1]; a2 += x2.x*w0[2];
            a3 += x2.x*w0[3]; a4 += x2.x*w0[4]; a5 += x2.x*w0[5];
            a6 += x2.x*w0[6]; a7 += x2.x*w0[7]; a8 += x2.x*w0[8];
            const float* w1 = w0 + 9;
            a0 += x2.y*w1[0]; a1 += x2.y*w1[1]; a2 += x2.y*w1[2];
            a3 += x2.y*w1[3]; a4 += x2.y*w1[4]; a5 += x2.y*w1[5];
            a6 += x2.y*w1[6]; a7 += x2.y*w1[7]; a8 += x2.y*w1[8];
        }
        float x = row[36];
        const float* wp = lw + 36 * 9;
        a0 += x*wp[0]; a1 += x*wp[1]; a2 += x*wp[2];
        a3 += x*wp[3]; a4 += x*wp[4]; a5 += x*wp[5];
        a6 += x*wp[6]; a7 += x*wp[7]; a8 += x*wp[8];
    } else {
        float x = row[37];
        const float* wp = lw + 37 * 9;
        a0 += x*wp[0]; a1 += x*wp[1]; a2 += x*wp[2];
        a3 += x*wp[3]; a4 += x*wp[4]; a5 += x*wp[5];
        a6 += x*wp[6]; a7 += x*wp[7]; a8 += x*wp[8];
        #pragma unroll
        for (int k = 0; k < 18; ++k) {
            float2 x2 = *(const float2*)(row + 38 + k * 2);
            const float* w0 = lw + (38 + k * 2) * 9;
            a0 += x2.x*w0[0]; a1 += x2.x*w0[1]; a2 += x2.x*w0[2];
            a3 += x2.x*w0[3]; a4 += x2.x*w0[4]; a5 += x2.x*w0[5];
            a6 += x2.x*w0[6]; a7 += x2.x*w0[7]; a8 += x2.x*w0[8];
            const float* w1 = w0 + 9;
            a0 += x2.y*w1[0]; a1 += x2.y*w1[1]; a2 += x2.y*w1[2];
            a3 += x2.y*w1[3]; a4 += x2.y*w1[4]; a5 += x2.y*w1[5];
            a6 += x2.y*w1[6]; a7 += x2.y*w1[7]; a8 += x2.y*w1[8];
        }
    }
    a0 += __shfl_xor(a0, 1, 64); a1 += __shfl_xor(a1, 1, 64);
    a2 += __shfl_xor(a2, 1, 64); a3 += __shfl_xor(a3, 1, 64);
    a4 += __shfl_xor(a4, 1, 64); a5 += __shfl_xor(a5, 1, 64);
    a6 += __shfl_xor(a6, 1, 64); a7 += __shfl_xor(a7, 1, 64);
    a8 += __shfl_xor(a8, 1, 64);
    if (!half) {
        sn4[node * 2]     = make_float4(a0, a1, a2, 0.f);  // el
        sn4[node * 2 + 1] = make_float4(a6, a7, a8, 0.f);  // hv
        er4[node]         = make_float4(a3, a4, a5, 0.f);
    }
}

// ---- D3 kProcess: cell-walk dense processing + fused pooling ----
__global__ __launch_bounds__(1024) void kProcess(const int* __restrict__ src,
        const int* __restrict__ ebuf, const int* __restrict__ cnt,
        const float4* __restrict__ sn4, const float4* __restrict__ er4,
        const float* __restrict__ bgvpar, const float* __restrict__ c0,
        float* __restrict__ y) {
    __shared__ float erL[SRNG * 4];   // 3.2 KB
    __shared__ float acc[SRNG * 6];   // 4.8 KB
    __shared__ int pref[NCH + 1];
    int tid = threadIdx.x, wave = tid >> 6, lane = tid & 63;
    const int r = blockIdx.x;
    __shared__ int cnts[NCH];
    if (tid < NCH) cnts[tid] = cnt[tid * SNR + r];
    for (int i = tid; i < SRNG * 6; i += 1024) acc[i] = 0.f;
    if (tid < SRNG) ((float4*)erL)[tid] = er4[(size_t)r * SRNG + tid];
    __syncthreads();
    if (tid == 0) {
        int b = 0;
        #pragma unroll
        for (int c = 0; c < NCH; ++c) { pref[c] = b; b += cnts[c]; }
        pref[NCH] = b;
    }
    __syncthreads();
    int T = pref[NCH];
    for (int i = tid; i < T; i += 1024) {
        int lo = 0, hi = NCH;
        while (hi - lo > 1) {
            int mid = (lo + hi) >> 1;
            if (pref[mid] <= i) lo = mid; else hi = mid;
        }
        int j = i - pref[lo];
        int pk = ebuf[(r * NCH + lo) * CAP + j];
        int rr = pk & 255;
        int e  = ((unsigned)pk) >> 8;
        int s  = src[e];
        float4 L = sn4[s * 2];
        float4 V = sn4[s * 2 + 1];
        const float* R = erL + rr * 4;
        float e0 = expf(lrelu02(L.x + R[0]));
        float e1 = expf(lrelu02(L.y + R[1]));
        float e2 = expf(lrelu02(L.z + R[2]));
        float* p = acc + rr * 6;
        atomicAdd(p + 0, e0 * V.x);
        atomicAdd(p + 1, e1 * V.y);
        atomicAdd(p + 2, e2 * V.z);
        atomicAdd(p + 3, e0);
        atomicAdd(p + 4, e1);
        atomicAdd(p + 5, e2);
    }
    __syncthreads();
    if (wave < 4) {
        float b = 0.f;
        for (int i = lane; i < NVB; i += 64) b += bgvpar[i];
        b = waveReduceSum(b);
        float cacc = 0.f;
        if (lane < 50) {
            const float* p = acc + (wave * 50 + lane) * 6;
            if (p[3] > 0.f) cacc = p[0] / p[3] + p[1] / p[4] + p[2] / p[5];
        }
        cacc = waveReduceSum(cacc);
        if (!lane) y[r * 4 + wave] = cacc * (1.f / 50.f) + b + c0[0];
    }
}

extern "C" void kernel_launch(void* const* d_in, const int* in_sizes, int n_in,
                              void* d_out, int out_size, void* d_ws, size_t ws_size,
                              hipStream_t stream) {
    const float* feats = (const float*)d_in[0];
    const float* W     = (const float*)d_in[1];
    const float* al    = (const float*)d_in[2];
    const float* ar    = (const float*)d_in[3];
    const float* bias  = (const float*)d_in[4];
    const float* W1    = (const float*)d_in[5];
    const float* b1    = (const float*)d_in[6];
    const float* W2    = (const float*)d_in[7];
    const float* b2    = (const float*)d_in[8];
    const int*   src   = (const int*)d_in[9];
    const int*   dst   = (const int*)d_in[10];

    float* ws      = (float*)d_ws;
    float* lw6     = ws;                      // 444 (pad 448)
    float* c0      = ws + 448;                // 1
    float* bgvpar  = ws + 512;                // 192
    float* wvpar   = ws + 1024;               // 222*64 = 14208
    int*   cnt     = (int*)(ws + 16384);      // 64*200 = 12800
    int*   ebuf    = (int*)(ws + 32768);      // 200*64*96 = 1228800
    float* sn      = ws + 1261568;            // N*8 (16B aligned)
    float* er      = sn + N_NODES * 8;        // N*4
    float* y       = (float*)d_out;

    hipLaunchKernelGGL(kPre, dim3(NVB + NTB + NCH), dim3(256), 0, stream,
                       W1, W2, b1, b2, W, al, ar, bias, dst,
                       c0, bgvpar, wvpar, lw6, cnt, ebuf);
    hipLaunchKernelGGL(kNode, dim3(NNB), dim3(256), 0, stream,
                       feats, lw6, wvpar, (float4*)sn, (float4*)er);
    hipLaunchKernelGGL(kProcess, dim3(SNR), dim3(1024), 0, stream,
                       src, ebuf, cnt, (const float4*)sn, (const float4*)er,
                       bgvpar, c0, y);
}